// Round 1
// baseline (9404.035 us; speedup 1.0000x reference)
//
#include <hip/hip_runtime.h>
#include <hip/hip_bf16.h>

#define D 64

__device__ __forceinline__ float selu_f(float x) {
    const float SC = 1.0507009873554805f;
    const float AL = 1.6732632423543772f;
    return x > 0.f ? SC * x : SC * AL * (expf(x) - 1.f);
}

// y[i][d] = sum_j Wmsg[d][j]   * x[i][j]   (main half)
// z[i][d] = sum_j Wmsg[d][64+j]* x[i][j]   (neighbour half)
__global__ void __launch_bounds__(1024) yz_kernel(const float* __restrict__ x,
                                                  const float* __restrict__ Wmsg,
                                                  float* __restrict__ y,
                                                  float* __restrict__ z, int N) {
    __shared__ float WT[128 * 64];  // WT[j][d] = Wmsg[d][j], j in [0,128)
    for (int idx = threadIdx.x; idx < 128 * 64; idx += blockDim.x) {
        int j = idx >> 6, d = idx & 63;
        WT[idx] = Wmsg[d * 128 + j];
    }
    __syncthreads();
    int lane = threadIdx.x & 63;
    int wave = blockIdx.x * (blockDim.x >> 6) + (threadIdx.x >> 6);
    int nwaves = gridDim.x * (blockDim.x >> 6);
    for (int i = wave; i < N; i += nwaves) {
        float xv = x[(size_t)i * D + lane];
        float accy = 0.f, accz = 0.f;
#pragma unroll
        for (int j = 0; j < 64; ++j) {
            float xj = __shfl(xv, j, 64);
            accy = fmaf(WT[j * 64 + lane], xj, accy);
            accz = fmaf(WT[(64 + j) * 64 + lane], xj, accz);
        }
        y[(size_t)i * D + lane] = accy;
        z[(size_t)i * D + lane] = accz;
    }
}

// per edge: m = selu(y[main] + z[neigh] + b); atomicAdd into M[neigh]
__global__ void __launch_bounds__(256) edge_kernel(const int* __restrict__ idm,
                                                   const int* __restrict__ idn,
                                                   const float* __restrict__ y,
                                                   const float* __restrict__ z,
                                                   const float* __restrict__ bmsg,
                                                   float* __restrict__ M, int E) {
    int lane = threadIdx.x & 63;
    int wave = blockIdx.x * (blockDim.x >> 6) + (threadIdx.x >> 6);
    int nwaves = gridDim.x * (blockDim.x >> 6);
    float b = bmsg[lane];
    for (int e = wave; e < E; e += nwaves) {
        int im = idm[e];
        int in = idn[e];
        float v = y[(size_t)im * D + lane] + z[(size_t)in * D + lane] + b;
        v = selu_f(v);
        atomicAdd(&M[(size_t)in * D + lane], v);
    }
}

// GRU cell per node, in-place update of h.
__global__ void __launch_bounds__(1024) gru_kernel(const float* __restrict__ M,
                                                   float* __restrict__ h,
                                                   const float* __restrict__ Wih,
                                                   const float* __restrict__ Whh,
                                                   const float* __restrict__ bih,
                                                   const float* __restrict__ bhh, int N) {
    // WL[j*384 + g*64 + d]: g=0..2 -> Wih rows {d, 64+d, 128+d} col j; g=3..5 -> Whh same
    __shared__ float WL[384 * 64];  // 96 KB
    for (int idx = threadIdx.x; idx < 384 * 64; idx += blockDim.x) {
        int j = idx / 384;
        int rem = idx - j * 384;
        int g = rem >> 6, d = rem & 63;
        if (g < 3)
            WL[idx] = Wih[(g * 64 + d) * 64 + j];
        else
            WL[idx] = Whh[((g - 3) * 64 + d) * 64 + j];
    }
    __syncthreads();
    int lane = threadIdx.x & 63;
    int wave = blockIdx.x * (blockDim.x >> 6) + (threadIdx.x >> 6);
    int nwaves = gridDim.x * (blockDim.x >> 6);
    float b_ir = bih[lane], b_iz = bih[64 + lane], b_in = bih[128 + lane];
    float b_hr = bhh[lane], b_hz = bhh[64 + lane], b_hn = bhh[128 + lane];
    for (int i = wave; i < N; i += nwaves) {
        float xm = M[(size_t)i * D + lane];
        float xh = h[(size_t)i * D + lane];
        float air = b_ir, aiz = b_iz, ain = b_in;
        float ahr = b_hr, ahz = b_hz, ahn = b_hn;
#pragma unroll
        for (int j = 0; j < 64; ++j) {
            float mj = __shfl(xm, j, 64);
            float hj = __shfl(xh, j, 64);
            const float* w = &WL[j * 384];
            air = fmaf(w[lane], mj, air);
            aiz = fmaf(w[64 + lane], mj, aiz);
            ain = fmaf(w[128 + lane], mj, ain);
            ahr = fmaf(w[192 + lane], hj, ahr);
            ahz = fmaf(w[256 + lane], hj, ahz);
            ahn = fmaf(w[320 + lane], hj, ahn);
        }
        float r = 1.f / (1.f + expf(-(air + ahr)));
        float zg = 1.f / (1.f + expf(-(aiz + ahz)));
        float n = tanhf(ain + r * ahn);
        h[(size_t)i * D + lane] = (1.f - zg) * n + zg * xh;
    }
}

__global__ void __launch_bounds__(256) pathsum_kernel(const float* __restrict__ h,
                                                      float* __restrict__ kp, int N, int K) {
    int per = N / K;  // 6250
    int blocksPerPath = gridDim.x / K;
    int p = blockIdx.x / blocksPerPath;
    int c = blockIdx.x % blocksPerPath;
    int d = threadIdx.x & 63;
    int row0 = c * (blockDim.x >> 6) + (threadIdx.x >> 6);
    int stride = blocksPerPath * (blockDim.x >> 6);
    float acc = 0.f;
    for (int r = row0; r < per; r += stride) acc += h[((size_t)p * per + r) * D + d];
    __shared__ float red[256];
    red[threadIdx.x] = acc;
    __syncthreads();
    if (threadIdx.x < 64) {
        float s = red[threadIdx.x] + red[64 + threadIdx.x] + red[128 + threadIdx.x] +
                  red[192 + threadIdx.x];
        atomicAdd(&kp[p * 64 + threadIdx.x], s);
    }
}

__global__ void __launch_bounds__(256) readout_kernel(const float* __restrict__ kp,
                                                      const float* __restrict__ Wr1,
                                                      const float* __restrict__ br1,
                                                      const float* __restrict__ Wr2,
                                                      const float* __restrict__ br2,
                                                      const float* __restrict__ Wr3,
                                                      const float* __restrict__ br3,
                                                      float* __restrict__ out) {
    const int K = 8;
    __shared__ float kps[K * 64];
    __shared__ float h1[K * 256];
    __shared__ float h2[K * 256];
    __shared__ float logits[K];
    int t = threadIdx.x;
    for (int idx = t; idx < K * 64; idx += 256) kps[idx] = kp[idx];
    __syncthreads();
    for (int p = 0; p < K; ++p) {
        float acc = br1[t];
#pragma unroll
        for (int d = 0; d < 64; ++d) acc = fmaf(Wr1[t * 64 + d], kps[p * 64 + d], acc);
        h1[p * 256 + t] = selu_f(acc);
    }
    __syncthreads();
    for (int p = 0; p < K; ++p) {
        float acc = br2[t];
        for (int j = 0; j < 256; ++j) acc = fmaf(Wr2[t * 256 + j], h1[p * 256 + j], acc);
        h2[p * 256 + t] = selu_f(acc);
    }
    __syncthreads();
    if (t < K) {
        float acc = br3[0];
        for (int j = 0; j < 256; ++j) acc = fmaf(Wr3[j], h2[t * 256 + j], acc);
        logits[t] = acc;
    }
    __syncthreads();
    if (t == 0) {
        float mx = logits[0];
        for (int p = 1; p < K; ++p) mx = fmaxf(mx, logits[p]);
        float s = 0.f, e[K];
        for (int p = 0; p < K; ++p) {
            e[p] = expf(logits[p] - mx);
            s += e[p];
        }
        for (int p = 0; p < K; ++p) out[p] = e[p] / s;
    }
}

extern "C" void kernel_launch(void* const* d_in, const int* in_sizes, int n_in,
                              void* d_out, int out_size, void* d_ws, size_t ws_size,
                              hipStream_t stream) {
    const float* links_state = (const float*)d_in[0];
    const int* idm = (const int*)d_in[1];
    const int* idn = (const int*)d_in[2];
    const float* Wmsg = (const float*)d_in[3];
    const float* bmsg = (const float*)d_in[4];
    const float* Wih = (const float*)d_in[5];
    const float* Whh = (const float*)d_in[6];
    const float* bih = (const float*)d_in[7];
    const float* bhh = (const float*)d_in[8];
    const float* Wr1 = (const float*)d_in[9];
    const float* br1 = (const float*)d_in[10];
    const float* Wr2 = (const float*)d_in[11];
    const float* br2 = (const float*)d_in[12];
    const float* Wr3 = (const float*)d_in[13];
    const float* br3 = (const float*)d_in[14];

    const int N = in_sizes[0] / D;  // 50000
    const int E = in_sizes[1];      // 800000
    const int K = 8, T = 3;

    float* ws = (float*)d_ws;
    size_t nd = (size_t)N * D;
    float* cur = ws;
    float* M = ws + nd;
    float* y = ws + 2 * nd;
    float* z = ws + 3 * nd;
    float* kp = ws + 4 * nd;

    hipMemcpyAsync(cur, links_state, nd * sizeof(float), hipMemcpyDeviceToDevice, stream);

    for (int t = 0; t < T; ++t) {
        hipMemsetAsync(M, 0, nd * sizeof(float), stream);
        yz_kernel<<<dim3(512), dim3(1024), 0, stream>>>(cur, Wmsg, y, z, N);
        edge_kernel<<<dim3(2048), dim3(256), 0, stream>>>(idm, idn, y, z, bmsg, M, E);
        gru_kernel<<<dim3(256), dim3(1024), 0, stream>>>(M, cur, Wih, Whh, bih, bhh, N);
    }

    hipMemsetAsync(kp, 0, (size_t)K * 64 * sizeof(float), stream);
    pathsum_kernel<<<dim3(256), dim3(256), 0, stream>>>(cur, kp, N, K);
    readout_kernel<<<dim3(1), dim3(256), 0, stream>>>(kp, Wr1, br1, Wr2, br2, Wr3, br3,
                                                      (float*)d_out);
}

// Round 2
// 7707.005 us; speedup vs baseline: 1.2202x; 1.2202x over previous
//
#include <hip/hip_runtime.h>
#include <hip/hip_bf16.h>

#define D 64

__device__ __forceinline__ float selu_f(float x) {
    const float SC = 1.0507009873554805f;
    const float AL = 1.6732632423543772f;
    return x > 0.f ? SC * x : SC * AL * (expf(x) - 1.f);
}

// y[i][d] = sum_j Wmsg[d][j]   * x[i][j]   (main half)
// z[i][d] = sum_j Wmsg[d][64+j]* x[i][j]   (neighbour half)
__global__ void __launch_bounds__(1024) yz_kernel(const float* __restrict__ x,
                                                  const float* __restrict__ Wmsg,
                                                  float* __restrict__ y,
                                                  float* __restrict__ z, int N) {
    __shared__ float WT[128 * 64];  // WT[j][d] = Wmsg[d][j], j in [0,128)
    for (int idx = threadIdx.x; idx < 128 * 64; idx += blockDim.x) {
        int j = idx >> 6, d = idx & 63;
        WT[idx] = Wmsg[d * 128 + j];
    }
    __syncthreads();
    int lane = threadIdx.x & 63;
    int wave = blockIdx.x * (blockDim.x >> 6) + (threadIdx.x >> 6);
    int nwaves = gridDim.x * (blockDim.x >> 6);
    for (int i = wave; i < N; i += nwaves) {
        float xv = x[(size_t)i * D + lane];
        float accy = 0.f, accz = 0.f;
#pragma unroll
        for (int j = 0; j < 64; ++j) {
            float xj = __shfl(xv, j, 64);
            accy = fmaf(WT[j * 64 + lane], xj, accy);
            accz = fmaf(WT[(64 + j) * 64 + lane], xj, accz);
        }
        y[(size_t)i * D + lane] = accy;
        z[(size_t)i * D + lane] = accz;
    }
}

// ---- CSR build (incoming edges keyed by id_neighbourEdges) ----
__global__ void __launch_bounds__(256) count_kernel(const int* __restrict__ idn,
                                                    int* __restrict__ cnt, int E) {
    int i = blockIdx.x * blockDim.x + threadIdx.x;
    if (i < E) atomicAdd(&cnt[idn[i]], 1);
}

__global__ void __launch_bounds__(1024) scan_kernel(const int* __restrict__ cnt,
                                                    int* __restrict__ row_start, int N) {
    __shared__ int part[1024];
    int t = threadIdx.x;
    int chunk = (N + 1023) / 1024;
    int lo = t * chunk;
    int hi = lo + chunk < N ? lo + chunk : N;
    int s = 0;
    for (int i = lo; i < hi; ++i) s += cnt[i];
    part[t] = s;
    __syncthreads();
    for (int off = 1; off < 1024; off <<= 1) {
        int v = part[t];
        int u = (t >= off) ? part[t - off] : 0;
        __syncthreads();
        part[t] = v + u;
        __syncthreads();
    }
    int excl = (t == 0) ? 0 : part[t - 1];
    for (int i = lo; i < hi; ++i) {
        row_start[i] = excl;
        excl += cnt[i];
    }
    if (t == 1023) row_start[N] = part[1023];
}

__global__ void __launch_bounds__(256) fill_kernel(const int* __restrict__ idm,
                                                   const int* __restrict__ idn,
                                                   const int* __restrict__ row_start,
                                                   int* __restrict__ cursor,
                                                   int* __restrict__ csr_src, int E) {
    int i = blockIdx.x * blockDim.x + threadIdx.x;
    if (i < E) {
        int n = idn[i];
        int p = atomicAdd(&cursor[n], 1);
        csr_src[row_start[n] + p] = idm[i];
    }
}

// ---- Fused aggregate (no atomics) + GRU update (in-place on h) ----
__global__ void __launch_bounds__(1024) agg_gru_kernel(
    const float* __restrict__ y, const float* __restrict__ z,
    const float* __restrict__ bmsg, const int* __restrict__ row_start,
    const int* __restrict__ csr_src, float* __restrict__ h,
    const float* __restrict__ Wih, const float* __restrict__ Whh,
    const float* __restrict__ bih, const float* __restrict__ bhh, int N) {
    // packed: Wi[j*192 + d*3 + g] = Wih[(g*64+d)*64 + j], g in {r,z,n}
    __shared__ float Wi[64 * 64 * 3];  // 48 KB
    __shared__ float Wh[64 * 64 * 3];  // 48 KB
    for (int idx = threadIdx.x; idx < 64 * 64 * 3; idx += blockDim.x) {
        int j = idx / 192;
        int rem = idx - j * 192;
        int d = rem / 3;
        int g = rem - d * 3;
        Wi[idx] = Wih[(g * 64 + d) * 64 + j];
        Wh[idx] = Whh[(g * 64 + d) * 64 + j];
    }
    __syncthreads();
    int lane = threadIdx.x & 63;
    int wave = blockIdx.x * (blockDim.x >> 6) + (threadIdx.x >> 6);
    int nwaves = gridDim.x * (blockDim.x >> 6);
    float b = bmsg[lane];
    float b_ir = bih[lane], b_iz = bih[64 + lane], b_in = bih[128 + lane];
    float b_hr = bhh[lane], b_hz = bhh[64 + lane], b_hn = bhh[128 + lane];
    for (int i = wave; i < N; i += nwaves) {
        float zb = z[(size_t)i * D + lane] + b;
        int s0 = row_start[i], s1 = row_start[i + 1];
        float macc = 0.f;
        int s = s0;
        for (; s + 4 <= s1; s += 4) {
            int e0 = csr_src[s], e1 = csr_src[s + 1];
            int e2 = csr_src[s + 2], e3 = csr_src[s + 3];
            float v0 = y[(size_t)e0 * D + lane];
            float v1 = y[(size_t)e1 * D + lane];
            float v2 = y[(size_t)e2 * D + lane];
            float v3 = y[(size_t)e3 * D + lane];
            macc += selu_f(v0 + zb);
            macc += selu_f(v1 + zb);
            macc += selu_f(v2 + zb);
            macc += selu_f(v3 + zb);
        }
        for (; s < s1; ++s) {
            int e0 = csr_src[s];
            macc += selu_f(y[(size_t)e0 * D + lane] + zb);
        }
        float hv = h[(size_t)i * D + lane];
        float air = b_ir, aiz = b_iz, ain = b_in;
        float ahr = b_hr, ahz = b_hz, ahn = b_hn;
#pragma unroll
        for (int j = 0; j < 64; ++j) {
            float mj = __shfl(macc, j, 64);
            float hj = __shfl(hv, j, 64);
            const float* wi = &Wi[j * 192 + lane * 3];
            const float* wh = &Wh[j * 192 + lane * 3];
            air = fmaf(wi[0], mj, air);
            aiz = fmaf(wi[1], mj, aiz);
            ain = fmaf(wi[2], mj, ain);
            ahr = fmaf(wh[0], hj, ahr);
            ahz = fmaf(wh[1], hj, ahz);
            ahn = fmaf(wh[2], hj, ahn);
        }
        float r = 1.f / (1.f + expf(-(air + ahr)));
        float zg = 1.f / (1.f + expf(-(aiz + ahz)));
        float n = tanhf(ain + r * ahn);
        h[(size_t)i * D + lane] = (1.f - zg) * n + zg * hv;
    }
}

__global__ void __launch_bounds__(256) pathsum_kernel(const float* __restrict__ h,
                                                      float* __restrict__ kp, int N, int K) {
    int per = N / K;  // 6250
    int blocksPerPath = gridDim.x / K;
    int p = blockIdx.x / blocksPerPath;
    int c = blockIdx.x % blocksPerPath;
    int d = threadIdx.x & 63;
    int row0 = c * (blockDim.x >> 6) + (threadIdx.x >> 6);
    int stride = blocksPerPath * (blockDim.x >> 6);
    float acc = 0.f;
    for (int r = row0; r < per; r += stride) acc += h[((size_t)p * per + r) * D + d];
    __shared__ float red[256];
    red[threadIdx.x] = acc;
    __syncthreads();
    if (threadIdx.x < 64) {
        float s = red[threadIdx.x] + red[64 + threadIdx.x] + red[128 + threadIdx.x] +
                  red[192 + threadIdx.x];
        atomicAdd(&kp[p * 64 + threadIdx.x], s);
    }
}

__global__ void __launch_bounds__(256) readout_kernel(const float* __restrict__ kp,
                                                      const float* __restrict__ Wr1,
                                                      const float* __restrict__ br1,
                                                      const float* __restrict__ Wr2,
                                                      const float* __restrict__ br2,
                                                      const float* __restrict__ Wr3,
                                                      const float* __restrict__ br3,
                                                      float* __restrict__ out) {
    const int K = 8;
    __shared__ float kps[K * 64];
    __shared__ float h1[K * 256];
    __shared__ float h2[K * 256];
    __shared__ float logits[K];
    int t = threadIdx.x;
    for (int idx = t; idx < K * 64; idx += 256) kps[idx] = kp[idx];
    __syncthreads();
    for (int p = 0; p < K; ++p) {
        float acc = br1[t];
#pragma unroll
        for (int d = 0; d < 64; ++d) acc = fmaf(Wr1[t * 64 + d], kps[p * 64 + d], acc);
        h1[p * 256 + t] = selu_f(acc);
    }
    __syncthreads();
    for (int p = 0; p < K; ++p) {
        float acc = br2[t];
        for (int j = 0; j < 256; ++j) acc = fmaf(Wr2[t * 256 + j], h1[p * 256 + j], acc);
        h2[p * 256 + t] = selu_f(acc);
    }
    __syncthreads();
    if (t < K) {
        float acc = br3[0];
        for (int j = 0; j < 256; ++j) acc = fmaf(Wr3[j], h2[t * 256 + j], acc);
        logits[t] = acc;
    }
    __syncthreads();
    if (t == 0) {
        float mx = logits[0];
        for (int p = 1; p < K; ++p) mx = fmaxf(mx, logits[p]);
        float s = 0.f, e[K];
        for (int p = 0; p < K; ++p) {
            e[p] = expf(logits[p] - mx);
            s += e[p];
        }
        for (int p = 0; p < K; ++p) out[p] = e[p] / s;
    }
}

extern "C" void kernel_launch(void* const* d_in, const int* in_sizes, int n_in,
                              void* d_out, int out_size, void* d_ws, size_t ws_size,
                              hipStream_t stream) {
    const float* links_state = (const float*)d_in[0];
    const int* idm = (const int*)d_in[1];
    const int* idn = (const int*)d_in[2];
    const float* Wmsg = (const float*)d_in[3];
    const float* bmsg = (const float*)d_in[4];
    const float* Wih = (const float*)d_in[5];
    const float* Whh = (const float*)d_in[6];
    const float* bih = (const float*)d_in[7];
    const float* bhh = (const float*)d_in[8];
    const float* Wr1 = (const float*)d_in[9];
    const float* br1 = (const float*)d_in[10];
    const float* Wr2 = (const float*)d_in[11];
    const float* br2 = (const float*)d_in[12];
    const float* Wr3 = (const float*)d_in[13];
    const float* br3 = (const float*)d_in[14];

    const int N = in_sizes[0] / D;  // 50000
    const int E = in_sizes[1];      // 800000
    const int K = 8, T = 3;

    float* ws = (float*)d_ws;
    size_t nd = (size_t)N * D;
    float* cur = ws;
    float* y = ws + nd;
    float* z = ws + 2 * nd;
    float* kp = ws + 3 * nd;
    int* ibase = (int*)(ws + 3 * nd + 512);
    int* cnt = ibase;               // N
    int* row_start = ibase + N;     // N+1
    int* cursor = ibase + 2 * N + 1;// N
    int* csr_src = ibase + 3 * N + 1;// E

    // CSR build (once per launch)
    hipMemsetAsync(cnt, 0, (size_t)N * sizeof(int), stream);
    hipMemsetAsync(cursor, 0, (size_t)N * sizeof(int), stream);
    count_kernel<<<dim3((E + 255) / 256), dim3(256), 0, stream>>>(idn, cnt, E);
    scan_kernel<<<dim3(1), dim3(1024), 0, stream>>>(cnt, row_start, N);
    fill_kernel<<<dim3((E + 255) / 256), dim3(256), 0, stream>>>(idm, idn, row_start, cursor,
                                                                 csr_src, E);

    hipMemcpyAsync(cur, links_state, nd * sizeof(float), hipMemcpyDeviceToDevice, stream);

    for (int t = 0; t < T; ++t) {
        yz_kernel<<<dim3(512), dim3(1024), 0, stream>>>(cur, Wmsg, y, z, N);
        agg_gru_kernel<<<dim3(256), dim3(1024), 0, stream>>>(y, z, bmsg, row_start, csr_src,
                                                             cur, Wih, Whh, bih, bhh, N);
    }

    hipMemsetAsync(kp, 0, (size_t)K * 64 * sizeof(float), stream);
    pathsum_kernel<<<dim3(256), dim3(256), 0, stream>>>(cur, kp, N, K);
    readout_kernel<<<dim3(1), dim3(256), 0, stream>>>(kp, Wr1, br1, Wr2, br2, Wr3, br3,
                                                      (float*)d_out);
}

// Round 3
// 6094.711 us; speedup vs baseline: 1.5430x; 1.2645x over previous
//
#include <hip/hip_runtime.h>
#include <hip/hip_bf16.h>

#define D 64

__device__ __forceinline__ float selu_f(float x) {
    const float SC = 1.0507009873554805f;
    const float AL = 1.6732632423543772f;
    return x > 0.f ? SC * x : SC * AL * (expf(x) - 1.f);
}

__device__ __forceinline__ float sigmoid_f(float x) { return 1.f / (1.f + expf(-x)); }

// y[i][d] = sum_j Wmsg[d][j] * x[i][j] ; z[i][d] = sum_j Wmsg[d][64+j] * x[i][j]
__global__ void __launch_bounds__(1024) yz_kernel(const float* __restrict__ x,
                                                  const float* __restrict__ Wmsg,
                                                  float* __restrict__ y,
                                                  float* __restrict__ z, int N) {
    __shared__ float WT[128 * 65];  // padded stride 65: conflict-free write & read
    for (int idx = threadIdx.x; idx < 128 * 64; idx += blockDim.x) {
        int d = idx >> 7, j = idx & 127;          // consecutive threads -> consecutive j
        WT[j * 65 + d] = Wmsg[d * 128 + j];       // coalesced global read
    }
    __syncthreads();
    int lane = threadIdx.x & 63;
    int wave = blockIdx.x * (blockDim.x >> 6) + (threadIdx.x >> 6);
    int nwaves = gridDim.x * (blockDim.x >> 6);
    for (int i = wave; i < N; i += nwaves) {
        float xv = x[(size_t)i * D + lane];
        float accy = 0.f, accz = 0.f;
#pragma unroll
        for (int j = 0; j < 64; ++j) {
            float xj = __shfl(xv, j, 64);
            accy = fmaf(WT[j * 65 + lane], xj, accy);
            accz = fmaf(WT[(64 + j) * 65 + lane], xj, accz);
        }
        y[(size_t)i * D + lane] = accy;
        z[(size_t)i * D + lane] = accz;
    }
}

// ---- CSR build (incoming edges keyed by id_neighbourEdges) ----
__global__ void __launch_bounds__(256) count_kernel(const int* __restrict__ idn,
                                                    int* __restrict__ cnt, int E) {
    int i = blockIdx.x * blockDim.x + threadIdx.x;
    if (i < E) atomicAdd(&cnt[idn[i]], 1);
}

__global__ void __launch_bounds__(1024) scan_kernel(const int* __restrict__ cnt,
                                                    int* __restrict__ row_start, int N) {
    __shared__ int part[1024];
    int t = threadIdx.x;
    int chunk = (N + 1023) / 1024;
    int lo = t * chunk;
    int hi = lo + chunk < N ? lo + chunk : N;
    int s = 0;
    for (int i = lo; i < hi; ++i) s += cnt[i];
    part[t] = s;
    __syncthreads();
    for (int off = 1; off < 1024; off <<= 1) {
        int v = part[t];
        int u = (t >= off) ? part[t - off] : 0;
        __syncthreads();
        part[t] = v + u;
        __syncthreads();
    }
    int excl = (t == 0) ? 0 : part[t - 1];
    for (int i = lo; i < hi; ++i) {
        row_start[i] = excl;
        excl += cnt[i];
    }
    if (t == 1023) row_start[N] = part[1023];
}

__global__ void __launch_bounds__(256) fill_kernel(const int* __restrict__ idm,
                                                   const int* __restrict__ idn,
                                                   const int* __restrict__ row_start,
                                                   int* __restrict__ cursor,
                                                   int* __restrict__ csr_src, int E) {
    int i = blockIdx.x * blockDim.x + threadIdx.x;
    if (i < E) {
        int n = idn[i];
        int p = atomicAdd(&cursor[n], 1);
        csr_src[row_start[n] + p] = idm[i];
    }
}

// K1: gh[i-n0][{r,z,n}*64+d] = bhh + h[i]·Whh^T   (48.25 KB LDS, 2 blocks/CU)
__global__ void __launch_bounds__(1024) gh_kernel(const float* __restrict__ h,
                                                  const float* __restrict__ Whh,
                                                  const float* __restrict__ bhh,
                                                  float* __restrict__ gh, int n0, int n1) {
    __shared__ float WT[64 * 193];  // WT[j*193 + r] = Whh[r][j], padded stride
    for (int idx = threadIdx.x; idx < 192 * 64; idx += blockDim.x) {
        int r = idx >> 6, j = idx & 63;
        WT[j * 193 + r] = Whh[r * 64 + j];  // coalesced read, conflict-free write
    }
    __syncthreads();
    int lane = threadIdx.x & 63;
    int wave = blockIdx.x * (blockDim.x >> 6) + (threadIdx.x >> 6);
    int nwaves = gridDim.x * (blockDim.x >> 6);
    float b_hr = bhh[lane], b_hz = bhh[64 + lane], b_hn = bhh[128 + lane];
    for (int i = n0 + wave; i < n1; i += nwaves) {
        float hv = h[(size_t)i * D + lane];
        float ahr = b_hr, ahz = b_hz, ahn = b_hn;
#pragma unroll
        for (int j = 0; j < 64; ++j) {
            float hj = __shfl(hv, j, 64);
            const float* w = &WT[j * 193];
            ahr = fmaf(w[lane], hj, ahr);
            ahz = fmaf(w[64 + lane], hj, ahz);
            ahn = fmaf(w[128 + lane], hj, ahn);
        }
        size_t o = (size_t)(i - n0) * 192;
        gh[o + lane] = ahr;
        gh[o + 64 + lane] = ahz;
        gh[o + 128 + lane] = ahn;
    }
}

// K2: gather+selu -> macc ; gi = macc·Wih^T + bih ; GRU combine with gh; write h
__global__ void __launch_bounds__(1024) agg_gi_gru_kernel(
    const float* __restrict__ y, const float* __restrict__ z,
    const float* __restrict__ bmsg, const int* __restrict__ row_start,
    const int* __restrict__ csr_src, const float* __restrict__ gh,
    float* __restrict__ h, const float* __restrict__ Wih,
    const float* __restrict__ bih, int n0, int n1) {
    __shared__ float WT[64 * 193];  // WT[j*193 + r] = Wih[r][j]
    for (int idx = threadIdx.x; idx < 192 * 64; idx += blockDim.x) {
        int r = idx >> 6, j = idx & 63;
        WT[j * 193 + r] = Wih[r * 64 + j];
    }
    __syncthreads();
    int lane = threadIdx.x & 63;
    int wave = blockIdx.x * (blockDim.x >> 6) + (threadIdx.x >> 6);
    int nwaves = gridDim.x * (blockDim.x >> 6);
    float b = bmsg[lane];
    float b_ir = bih[lane], b_iz = bih[64 + lane], b_in = bih[128 + lane];
    for (int i = n0 + wave; i < n1; i += nwaves) {
        float zb = z[(size_t)i * D + lane] + b;
        int s0 = row_start[i], s1 = row_start[i + 1];
        float macc = 0.f;
        int s = s0;
        for (; s + 4 <= s1; s += 4) {
            int e0 = csr_src[s], e1 = csr_src[s + 1];
            int e2 = csr_src[s + 2], e3 = csr_src[s + 3];
            float v0 = y[(size_t)e0 * D + lane];
            float v1 = y[(size_t)e1 * D + lane];
            float v2 = y[(size_t)e2 * D + lane];
            float v3 = y[(size_t)e3 * D + lane];
            macc += selu_f(v0 + zb);
            macc += selu_f(v1 + zb);
            macc += selu_f(v2 + zb);
            macc += selu_f(v3 + zb);
        }
        for (; s < s1; ++s) {
            macc += selu_f(y[(size_t)csr_src[s] * D + lane] + zb);
        }
        float air = b_ir, aiz = b_iz, ain = b_in;
#pragma unroll
        for (int j = 0; j < 64; ++j) {
            float mj = __shfl(macc, j, 64);
            const float* w = &WT[j * 193];
            air = fmaf(w[lane], mj, air);
            aiz = fmaf(w[64 + lane], mj, aiz);
            ain = fmaf(w[128 + lane], mj, ain);
        }
        size_t o = (size_t)(i - n0) * 192;
        float ahr = gh[o + lane];
        float ahz = gh[o + 64 + lane];
        float ahn = gh[o + 128 + lane];
        float hv = h[(size_t)i * D + lane];
        float r = sigmoid_f(air + ahr);
        float zg = sigmoid_f(aiz + ahz);
        float n = tanhf(ain + r * ahn);
        h[(size_t)i * D + lane] = (1.f - zg) * n + zg * hv;
    }
}

__global__ void __launch_bounds__(256) pathsum_kernel(const float* __restrict__ h,
                                                      float* __restrict__ kp, int N, int K) {
    int per = N / K;  // 6250
    int blocksPerPath = gridDim.x / K;
    int p = blockIdx.x / blocksPerPath;
    int c = blockIdx.x % blocksPerPath;
    int d = threadIdx.x & 63;
    int row0 = c * (blockDim.x >> 6) + (threadIdx.x >> 6);
    int stride = blocksPerPath * (blockDim.x >> 6);
    float acc = 0.f;
    for (int r = row0; r < per; r += stride) acc += h[((size_t)p * per + r) * D + d];
    __shared__ float red[256];
    red[threadIdx.x] = acc;
    __syncthreads();
    if (threadIdx.x < 64) {
        float s = red[threadIdx.x] + red[64 + threadIdx.x] + red[128 + threadIdx.x] +
                  red[192 + threadIdx.x];
        atomicAdd(&kp[p * 64 + threadIdx.x], s);
    }
}

__global__ void __launch_bounds__(256) readout_kernel(const float* __restrict__ kp,
                                                      const float* __restrict__ Wr1,
                                                      const float* __restrict__ br1,
                                                      const float* __restrict__ Wr2,
                                                      const float* __restrict__ br2,
                                                      const float* __restrict__ Wr3,
                                                      const float* __restrict__ br3,
                                                      float* __restrict__ out) {
    const int K = 8;
    __shared__ float kps[K * 64];
    __shared__ float h1[K * 256];
    __shared__ float h2[K * 256];
    __shared__ float logits[K];
    int t = threadIdx.x;
    for (int idx = t; idx < K * 64; idx += 256) kps[idx] = kp[idx];
    __syncthreads();
    for (int p = 0; p < K; ++p) {
        float acc = br1[t];
#pragma unroll
        for (int d = 0; d < 64; ++d) acc = fmaf(Wr1[t * 64 + d], kps[p * 64 + d], acc);
        h1[p * 256 + t] = selu_f(acc);
    }
    __syncthreads();
    for (int p = 0; p < K; ++p) {
        float acc = br2[t];
        for (int j = 0; j < 256; ++j) acc = fmaf(Wr2[t * 256 + j], h1[p * 256 + j], acc);
        h2[p * 256 + t] = selu_f(acc);
    }
    __syncthreads();
    if (t < K) {
        float acc = br3[0];
        for (int j = 0; j < 256; ++j) acc = fmaf(Wr3[j], h2[t * 256 + j], acc);
        logits[t] = acc;
    }
    __syncthreads();
    if (t == 0) {
        float mx = logits[0];
        for (int p = 1; p < K; ++p) mx = fmaxf(mx, logits[p]);
        float s = 0.f, e[K];
        for (int p = 0; p < K; ++p) {
            e[p] = expf(logits[p] - mx);
            s += e[p];
        }
        for (int p = 0; p < K; ++p) out[p] = e[p] / s;
    }
}

extern "C" void kernel_launch(void* const* d_in, const int* in_sizes, int n_in,
                              void* d_out, int out_size, void* d_ws, size_t ws_size,
                              hipStream_t stream) {
    const float* links_state = (const float*)d_in[0];
    const int* idm = (const int*)d_in[1];
    const int* idn = (const int*)d_in[2];
    const float* Wmsg = (const float*)d_in[3];
    const float* bmsg = (const float*)d_in[4];
    const float* Wih = (const float*)d_in[5];
    const float* Whh = (const float*)d_in[6];
    const float* bih = (const float*)d_in[7];
    const float* bhh = (const float*)d_in[8];
    const float* Wr1 = (const float*)d_in[9];
    const float* br1 = (const float*)d_in[10];
    const float* Wr2 = (const float*)d_in[11];
    const float* br2 = (const float*)d_in[12];
    const float* Wr3 = (const float*)d_in[13];
    const float* br3 = (const float*)d_in[14];

    const int N = in_sizes[0] / D;  // 50000
    const int E = in_sizes[1];      // 800000
    const int K = 8, T = 3;
    const int NCHUNK = 5;
    const int CH = N / NCHUNK;  // 10000

    float* ws = (float*)d_ws;
    size_t nd = (size_t)N * D;
    float* cur = ws;
    float* y = ws + nd;
    float* z = ws + 2 * nd;
    float* ghbuf = ws + 3 * nd;                    // CH*192 floats
    float* kp = ghbuf + (size_t)CH * 192;          // 512 floats
    int* ibase = (int*)(kp + 512);
    int* cnt = ibase;                 // N
    int* row_start = ibase + N;       // N+1
    int* cursor = ibase + 2 * N + 1;  // N
    int* csr_src = ibase + 3 * N + 1; // E

    // CSR build (once per launch)
    hipMemsetAsync(cnt, 0, (size_t)N * sizeof(int), stream);
    hipMemsetAsync(cursor, 0, (size_t)N * sizeof(int), stream);
    count_kernel<<<dim3((E + 255) / 256), dim3(256), 0, stream>>>(idn, cnt, E);
    scan_kernel<<<dim3(1), dim3(1024), 0, stream>>>(cnt, row_start, N);
    fill_kernel<<<dim3((E + 255) / 256), dim3(256), 0, stream>>>(idm, idn, row_start, cursor,
                                                                 csr_src, E);

    hipMemcpyAsync(cur, links_state, nd * sizeof(float), hipMemcpyDeviceToDevice, stream);

    for (int t = 0; t < T; ++t) {
        yz_kernel<<<dim3(512), dim3(1024), 0, stream>>>(cur, Wmsg, y, z, N);
        for (int c = 0; c < NCHUNK; ++c) {
            int n0 = c * CH, n1 = n0 + CH;
            gh_kernel<<<dim3(512), dim3(1024), 0, stream>>>(cur, Whh, bhh, ghbuf, n0, n1);
            agg_gi_gru_kernel<<<dim3(512), dim3(1024), 0, stream>>>(
                y, z, bmsg, row_start, csr_src, ghbuf, cur, Wih, bih, n0, n1);
        }
    }

    hipMemsetAsync(kp, 0, (size_t)K * 64 * sizeof(float), stream);
    pathsum_kernel<<<dim3(256), dim3(256), 0, stream>>>(cur, kp, N, K);
    readout_kernel<<<dim3(1), dim3(256), 0, stream>>>(kp, Wr1, br1, Wr2, br2, Wr3, br3,
                                                      (float*)d_out);
}

// Round 4
// 1186.266 us; speedup vs baseline: 7.9274x; 5.1377x over previous
//
#include <hip/hip_runtime.h>
#include <hip/hip_bf16.h>

#define D 64

__device__ __forceinline__ float selu_f(float x) {
    const float SC = 1.0507009873554805f;
    const float AL = 1.6732632423543772f;
    return x > 0.f ? SC * x : SC * AL * (expf(x) - 1.f);
}

__device__ __forceinline__ float sigmoid_f(float x) { return 1.f / (1.f + expf(-x)); }

// y[i][d] = sum_j Wmsg[d][j] * x[i][j] ; z[i][d] = sum_j Wmsg[d][64+j] * x[i][j]
__global__ void __launch_bounds__(1024) yz_kernel(const float* __restrict__ x,
                                                  const float* __restrict__ Wmsg,
                                                  float* __restrict__ y,
                                                  float* __restrict__ z, int N) {
    __shared__ float WT[128 * 65];  // padded stride 65: conflict-free write & read
    for (int idx = threadIdx.x; idx < 128 * 64; idx += blockDim.x) {
        int d = idx >> 7, j = idx & 127;          // consecutive threads -> consecutive j
        WT[j * 65 + d] = Wmsg[d * 128 + j];       // coalesced global read
    }
    __syncthreads();
    int lane = threadIdx.x & 63;
    int wave = blockIdx.x * (blockDim.x >> 6) + (threadIdx.x >> 6);
    int nwaves = gridDim.x * (blockDim.x >> 6);
    for (int i = wave; i < N; i += nwaves) {
        float xv = x[(size_t)i * D + lane];
        float accy = 0.f, accz = 0.f;
#pragma unroll 4
        for (int j = 0; j < 64; ++j) {
            float xj = __shfl(xv, j, 64);
            accy = fmaf(WT[j * 65 + lane], xj, accy);
            accz = fmaf(WT[(64 + j) * 65 + lane], xj, accz);
        }
        y[(size_t)i * D + lane] = accy;
        z[(size_t)i * D + lane] = accz;
    }
}

// ---- CSR build (incoming edges keyed by id_neighbourEdges) ----
__global__ void __launch_bounds__(256) count_kernel(const int* __restrict__ idn,
                                                    int* __restrict__ cnt, int E) {
    int i = blockIdx.x * blockDim.x + threadIdx.x;
    if (i < E) atomicAdd(&cnt[idn[i]], 1);
}

__global__ void __launch_bounds__(1024) scan_kernel(const int* __restrict__ cnt,
                                                    int* __restrict__ row_start, int N) {
    __shared__ int part[1024];
    int t = threadIdx.x;
    int chunk = (N + 1023) / 1024;
    int lo = t * chunk;
    int hi = lo + chunk < N ? lo + chunk : N;
    int s = 0;
    for (int i = lo; i < hi; ++i) s += cnt[i];
    part[t] = s;
    __syncthreads();
    for (int off = 1; off < 1024; off <<= 1) {
        int v = part[t];
        int u = (t >= off) ? part[t - off] : 0;
        __syncthreads();
        part[t] = v + u;
        __syncthreads();
    }
    int excl = (t == 0) ? 0 : part[t - 1];
    for (int i = lo; i < hi; ++i) {
        row_start[i] = excl;
        excl += cnt[i];
    }
    if (t == 1023) row_start[N] = part[1023];
}

__global__ void __launch_bounds__(256) fill_kernel(const int* __restrict__ idm,
                                                   const int* __restrict__ idn,
                                                   const int* __restrict__ row_start,
                                                   int* __restrict__ cursor,
                                                   int* __restrict__ csr_src, int E) {
    int i = blockIdx.x * blockDim.x + threadIdx.x;
    if (i < E) {
        int n = idn[i];
        int p = atomicAdd(&cursor[n], 1);
        csr_src[row_start[n] + p] = idm[i];
    }
}

// K1: gh[i-n0][{r,z,n}*64+d] = bhh + h[i]·Whh^T   (48.25 KB LDS)
__global__ void __launch_bounds__(1024) gh_kernel(const float* __restrict__ h,
                                                  const float* __restrict__ Whh,
                                                  const float* __restrict__ bhh,
                                                  float* __restrict__ gh, int n0, int n1) {
    __shared__ float WT[64 * 193];  // WT[j*193 + r] = Whh[r][j], padded stride
    for (int idx = threadIdx.x; idx < 192 * 64; idx += blockDim.x) {
        int r = idx >> 6, j = idx & 63;
        WT[j * 193 + r] = Whh[r * 64 + j];  // coalesced read, conflict-free write
    }
    __syncthreads();
    int lane = threadIdx.x & 63;
    int wave = blockIdx.x * (blockDim.x >> 6) + (threadIdx.x >> 6);
    int nwaves = gridDim.x * (blockDim.x >> 6);
    float b_hr = bhh[lane], b_hz = bhh[64 + lane], b_hn = bhh[128 + lane];
    for (int i = n0 + wave; i < n1; i += nwaves) {
        float hv = h[(size_t)i * D + lane];
        float ahr = b_hr, ahz = b_hz, ahn = b_hn;
#pragma unroll 4
        for (int j = 0; j < 64; ++j) {
            float hj = __shfl(hv, j, 64);
            const float* w = &WT[j * 193];
            ahr = fmaf(w[lane], hj, ahr);
            ahz = fmaf(w[64 + lane], hj, ahz);
            ahn = fmaf(w[128 + lane], hj, ahn);
        }
        size_t o = (size_t)(i - n0) * 192;
        gh[o + lane] = ahr;
        gh[o + 64 + lane] = ahz;
        gh[o + 128 + lane] = ahn;
    }
}

// K2: gather+selu -> macc ; gi = macc·Wih^T + bih ; GRU combine with gh; write h
__global__ void __launch_bounds__(1024) agg_gi_gru_kernel(
    const float* __restrict__ y, const float* __restrict__ z,
    const float* __restrict__ bmsg, const int* __restrict__ row_start,
    const int* __restrict__ csr_src, const float* __restrict__ gh,
    float* __restrict__ h, const float* __restrict__ Wih,
    const float* __restrict__ bih, int n0, int n1) {
    __shared__ float WT[64 * 193];  // WT[j*193 + r] = Wih[r][j]
    for (int idx = threadIdx.x; idx < 192 * 64; idx += blockDim.x) {
        int r = idx >> 6, j = idx & 63;
        WT[j * 193 + r] = Wih[r * 64 + j];
    }
    __syncthreads();
    int lane = threadIdx.x & 63;
    int wave = blockIdx.x * (blockDim.x >> 6) + (threadIdx.x >> 6);
    int nwaves = gridDim.x * (blockDim.x >> 6);
    float b = bmsg[lane];
    float b_ir = bih[lane], b_iz = bih[64 + lane], b_in = bih[128 + lane];
    for (int i = n0 + wave; i < n1; i += nwaves) {
        float zb = z[(size_t)i * D + lane] + b;
        int s0 = row_start[i], s1 = row_start[i + 1];
        float macc = 0.f;
        int s = s0;
        for (; s + 4 <= s1; s += 4) {
            int e0 = csr_src[s], e1 = csr_src[s + 1];
            int e2 = csr_src[s + 2], e3 = csr_src[s + 3];
            float v0 = y[(size_t)e0 * D + lane];
            float v1 = y[(size_t)e1 * D + lane];
            float v2 = y[(size_t)e2 * D + lane];
            float v3 = y[(size_t)e3 * D + lane];
            macc += selu_f(v0 + zb);
            macc += selu_f(v1 + zb);
            macc += selu_f(v2 + zb);
            macc += selu_f(v3 + zb);
        }
        for (; s < s1; ++s) {
            macc += selu_f(y[(size_t)csr_src[s] * D + lane] + zb);
        }
        float air = b_ir, aiz = b_iz, ain = b_in;
#pragma unroll 4
        for (int j = 0; j < 64; ++j) {
            float mj = __shfl(macc, j, 64);
            const float* w = &WT[j * 193];
            air = fmaf(w[lane], mj, air);
            aiz = fmaf(w[64 + lane], mj, aiz);
            ain = fmaf(w[128 + lane], mj, ain);
        }
        size_t o = (size_t)(i - n0) * 192;
        float ahr = gh[o + lane];
        float ahz = gh[o + 64 + lane];
        float ahn = gh[o + 128 + lane];
        float hv = h[(size_t)i * D + lane];
        float r = sigmoid_f(air + ahr);
        float zg = sigmoid_f(aiz + ahz);
        float n = tanhf(ain + r * ahn);
        h[(size_t)i * D + lane] = (1.f - zg) * n + zg * hv;
    }
}

__global__ void __launch_bounds__(256) pathsum_kernel(const float* __restrict__ h,
                                                      float* __restrict__ kp, int N, int K) {
    int per = N / K;  // 6250
    int blocksPerPath = gridDim.x / K;
    int p = blockIdx.x / blocksPerPath;
    int c = blockIdx.x % blocksPerPath;
    int d = threadIdx.x & 63;
    int row0 = c * (blockDim.x >> 6) + (threadIdx.x >> 6);
    int stride = blocksPerPath * (blockDim.x >> 6);
    float acc = 0.f;
    for (int r = row0; r < per; r += stride) acc += h[((size_t)p * per + r) * D + d];
    __shared__ float red[256];
    red[threadIdx.x] = acc;
    __syncthreads();
    if (threadIdx.x < 64) {
        float s = red[threadIdx.x] + red[64 + threadIdx.x] + red[128 + threadIdx.x] +
                  red[192 + threadIdx.x];
        atomicAdd(&kp[p * 64 + threadIdx.x], s);
    }
}

__global__ void __launch_bounds__(256) readout_kernel(const float* __restrict__ kp,
                                                      const float* __restrict__ Wr1,
                                                      const float* __restrict__ br1,
                                                      const float* __restrict__ Wr2,
                                                      const float* __restrict__ br2,
                                                      const float* __restrict__ Wr3,
                                                      const float* __restrict__ br3,
                                                      float* __restrict__ out) {
    const int K = 8;
    __shared__ float kps[K * 64];
    __shared__ float h1[K * 256];
    __shared__ float h2[K * 256];
    __shared__ float logits[K];
    int t = threadIdx.x;
    for (int idx = t; idx < K * 64; idx += 256) kps[idx] = kp[idx];
    __syncthreads();
    for (int p = 0; p < K; ++p) {
        float acc = br1[t];
#pragma unroll 4
        for (int d = 0; d < 64; ++d) acc = fmaf(Wr1[t * 64 + d], kps[p * 64 + d], acc);
        h1[p * 256 + t] = selu_f(acc);
    }
    __syncthreads();
    for (int p = 0; p < K; ++p) {
        float acc = br2[t];
#pragma unroll 4
        for (int j = 0; j < 256; ++j) acc = fmaf(Wr2[t * 256 + j], h1[p * 256 + j], acc);
        h2[p * 256 + t] = selu_f(acc);
    }
    __syncthreads();
    if (t < K) {
        float acc = br3[0];
        for (int j = 0; j < 256; ++j) acc = fmaf(Wr3[j], h2[t * 256 + j], acc);
        logits[t] = acc;
    }
    __syncthreads();
    if (t == 0) {
        float mx = logits[0];
        for (int p = 1; p < K; ++p) mx = fmaxf(mx, logits[p]);
        float s = 0.f, e[K];
        for (int p = 0; p < K; ++p) {
            e[p] = expf(logits[p] - mx);
            s += e[p];
        }
        for (int p = 0; p < K; ++p) out[p] = e[p] / s;
    }
}

extern "C" void kernel_launch(void* const* d_in, const int* in_sizes, int n_in,
                              void* d_out, int out_size, void* d_ws, size_t ws_size,
                              hipStream_t stream) {
    const float* links_state = (const float*)d_in[0];
    const int* idm = (const int*)d_in[1];
    const int* idn = (const int*)d_in[2];
    const float* Wmsg = (const float*)d_in[3];
    const float* bmsg = (const float*)d_in[4];
    const float* Wih = (const float*)d_in[5];
    const float* Whh = (const float*)d_in[6];
    const float* bih = (const float*)d_in[7];
    const float* bhh = (const float*)d_in[8];
    const float* Wr1 = (const float*)d_in[9];
    const float* br1 = (const float*)d_in[10];
    const float* Wr2 = (const float*)d_in[11];
    const float* br2 = (const float*)d_in[12];
    const float* Wr3 = (const float*)d_in[13];
    const float* br3 = (const float*)d_in[14];

    const int N = in_sizes[0] / D;  // 50000
    const int E = in_sizes[1];      // 800000
    const int K = 8, T = 3;
    const int NCHUNK = 5;
    const int CH = N / NCHUNK;  // 10000

    float* ws = (float*)d_ws;
    size_t nd = (size_t)N * D;
    float* cur = ws;
    float* y = ws + nd;
    float* z = ws + 2 * nd;
    float* ghbuf = ws + 3 * nd;                    // CH*192 floats
    float* kp = ghbuf + (size_t)CH * 192;          // 512 floats
    int* ibase = (int*)(kp + 512);
    int* cnt = ibase;                 // N
    int* row_start = ibase + N;       // N+1
    int* cursor = ibase + 2 * N + 1;  // N
    int* csr_src = ibase + 3 * N + 1; // E

    // CSR build (once per launch)
    hipMemsetAsync(cnt, 0, (size_t)N * sizeof(int), stream);
    hipMemsetAsync(cursor, 0, (size_t)N * sizeof(int), stream);
    count_kernel<<<dim3((E + 255) / 256), dim3(256), 0, stream>>>(idn, cnt, E);
    scan_kernel<<<dim3(1), dim3(1024), 0, stream>>>(cnt, row_start, N);
    fill_kernel<<<dim3((E + 255) / 256), dim3(256), 0, stream>>>(idm, idn, row_start, cursor,
                                                                 csr_src, E);

    hipMemcpyAsync(cur, links_state, nd * sizeof(float), hipMemcpyDeviceToDevice, stream);

    for (int t = 0; t < T; ++t) {
        yz_kernel<<<dim3(512), dim3(1024), 0, stream>>>(cur, Wmsg, y, z, N);
        for (int c = 0; c < NCHUNK; ++c) {
            int n0 = c * CH, n1 = n0 + CH;
            gh_kernel<<<dim3(512), dim3(1024), 0, stream>>>(cur, Whh, bhh, ghbuf, n0, n1);
            agg_gi_gru_kernel<<<dim3(512), dim3(1024), 0, stream>>>(
                y, z, bmsg, row_start, csr_src, ghbuf, cur, Wih, bih, n0, n1);
        }
    }

    hipMemsetAsync(kp, 0, (size_t)K * 64 * sizeof(float), stream);
    pathsum_kernel<<<dim3(256), dim3(256), 0, stream>>>(cur, kp, N, K);
    readout_kernel<<<dim3(1), dim3(256), 0, stream>>>(kp, Wr1, br1, Wr2, br2, Wr3, br3,
                                                      (float*)d_out);
}

// Round 5
// 965.688 us; speedup vs baseline: 9.7382x; 1.2284x over previous
//
#include <hip/hip_runtime.h>
#include <hip/hip_bf16.h>

#define D 64
#define NB 8      // nodes per wave-block
#define WPAD 68   // padded weight stride (floats), 16B-aligned, bank-spread

__device__ __forceinline__ float selu_f(float x) {
    const float SC = 1.0507009873554805f;
    const float AL = 1.6732632423543772f;
    return x > 0.f ? SC * x : SC * AL * (expf(x) - 1.f);
}
__device__ __forceinline__ float sigmoid_f(float x) { return 1.f / (1.f + expf(-x)); }
__device__ __forceinline__ float dot4(float4 a, float4 b, float acc) {
    acc = fmaf(a.x, b.x, acc);
    acc = fmaf(a.y, b.y, acc);
    acc = fmaf(a.z, b.z, acc);
    return fmaf(a.w, b.w, acc);
}

// ---- A: y = x@Wy^T, z = x@Wz^T (Wy = Wmsg[:,:64], Wz = Wmsg[:,64:]) ----
__global__ void __launch_bounds__(1024) yz_kernel(const float* __restrict__ x,
                                                  const float* __restrict__ Wmsg,
                                                  float* __restrict__ y,
                                                  float* __restrict__ z, int N) {
    __shared__ __align__(16) float wbuf[2 * 64 * WPAD];  // 34 KB
    __shared__ __align__(16) float xs[16 * NB * 64];     // 32 KB
    for (int idx = threadIdx.x; idx < 2 * 64 * 64; idx += 1024) {
        int g = idx >> 12, rem = idx & 4095;
        int d = rem >> 6, j = rem & 63;
        wbuf[g * 64 * WPAD + d * WPAD + j] = Wmsg[d * 128 + g * 64 + j];
    }
    __syncthreads();
    int lane = threadIdx.x & 63;
    int w = threadIdx.x >> 6;
    float* xw = &xs[w * (NB * 64)];
    const float* wy = wbuf;
    const float* wz = wbuf + 64 * WPAD;
    int nbTot = (N + NB - 1) / NB;
    for (int nb = blockIdx.x * 16 + w; nb < nbTot; nb += gridDim.x * 16) {
        int n0 = nb * NB;
#pragma unroll
        for (int n = 0; n < NB; ++n) {
            int i = n0 + n;
            xw[n * 64 + lane] = (i < N) ? x[(size_t)i * 64 + lane] : 0.f;
        }
        float accy[NB], accz[NB];
#pragma unroll
        for (int n = 0; n < NB; ++n) { accy[n] = 0.f; accz[n] = 0.f; }
#pragma unroll 1
        for (int jg = 0; jg < 16; ++jg) {
            float4 wyv = *(const float4*)&wy[lane * WPAD + jg * 4];
            float4 wzv = *(const float4*)&wz[lane * WPAD + jg * 4];
#pragma unroll
            for (int n = 0; n < NB; ++n) {
                float4 xv = *(const float4*)&xw[n * 64 + jg * 4];  // uniform: broadcast
                accy[n] = dot4(wyv, xv, accy[n]);
                accz[n] = dot4(wzv, xv, accz[n]);
            }
        }
#pragma unroll
        for (int n = 0; n < NB; ++n) {
            int i = n0 + n;
            if (i < N) {
                y[(size_t)i * 64 + lane] = accy[n];
                z[(size_t)i * 64 + lane] = accz[n];
            }
        }
    }
}

// ---- CSR build ----
__global__ void __launch_bounds__(256) count_kernel(const int* __restrict__ idn,
                                                    int* __restrict__ cnt, int E) {
    int i = blockIdx.x * blockDim.x + threadIdx.x;
    if (i < E) atomicAdd(&cnt[idn[i]], 1);
}

__global__ void __launch_bounds__(1024) scan_kernel(const int* __restrict__ cnt,
                                                    int* __restrict__ row_start, int N) {
    __shared__ int part[1024];
    int t = threadIdx.x;
    int chunk = (N + 1023) / 1024;
    int lo = t * chunk;
    int hi = lo + chunk < N ? lo + chunk : N;
    int s = 0;
    for (int i = lo; i < hi; ++i) s += cnt[i];
    part[t] = s;
    __syncthreads();
    for (int off = 1; off < 1024; off <<= 1) {
        int v = part[t];
        int u = (t >= off) ? part[t - off] : 0;
        __syncthreads();
        part[t] = v + u;
        __syncthreads();
    }
    int excl = (t == 0) ? 0 : part[t - 1];
    for (int i = lo; i < hi; ++i) {
        row_start[i] = excl;
        excl += cnt[i];
    }
    if (t == 1023) row_start[N] = part[1023];
}

__global__ void __launch_bounds__(256) fill_kernel(const int* __restrict__ idm,
                                                   const int* __restrict__ idn,
                                                   const int* __restrict__ row_start,
                                                   int* __restrict__ cursor,
                                                   int* __restrict__ csr_src, int E) {
    int i = blockIdx.x * blockDim.x + threadIdx.x;
    if (i < E) {
        int n = idn[i];
        int p = atomicAdd(&cursor[n], 1);
        csr_src[row_start[n] + p] = idm[i];
    }
}

// ---- B: gather+selu -> M ; gi = M@Wih^T ; gh = h@Whh^T ; GRU combine ----
__global__ void __launch_bounds__(512) void_step_guard();  // (unused decl guard)
__global__ void __launch_bounds__(512) step_kernel(
    const float* __restrict__ y, const float* __restrict__ z,
    float* __restrict__ cur, const float* __restrict__ bmsg,
    const int* __restrict__ row_start, const int* __restrict__ csr_src,
    const float* __restrict__ Wih, const float* __restrict__ Whh,
    const float* __restrict__ bih, const float* __restrict__ bhh, int N) {
    __shared__ __align__(16) float wbuf[6 * 64 * WPAD];  // 104.4 KB
    __shared__ __align__(16) float xsM[8 * NB * 64];     // 16 KB
    __shared__ __align__(16) float xsH[8 * NB * 64];     // 16 KB
    for (int idx = threadIdx.x; idx < 6 * 64 * 64; idx += 512) {
        int g = idx >> 12, rem = idx & 4095;
        int d = rem >> 6, j = rem & 63;
        const float* src = (g < 3) ? Wih : Whh;
        int gg = (g < 3) ? g : g - 3;
        wbuf[g * 64 * WPAD + d * WPAD + j] = src[(gg * 64 + d) * 64 + j];
    }
    __syncthreads();
    int lane = threadIdx.x & 63;
    int w = threadIdx.x >> 6;
    float* xm = &xsM[w * (NB * 64)];
    float* xh = &xsH[w * (NB * 64)];
    const float* wir = wbuf + 0 * 64 * WPAD;
    const float* wiz = wbuf + 1 * 64 * WPAD;
    const float* win = wbuf + 2 * 64 * WPAD;
    const float* whr = wbuf + 3 * 64 * WPAD;
    const float* whz = wbuf + 4 * 64 * WPAD;
    const float* whn = wbuf + 5 * 64 * WPAD;
    float b = bmsg[lane];
    float bir = bih[lane], biz = bih[64 + lane], bin_ = bih[128 + lane];
    float bhr = bhh[lane], bhz = bhh[64 + lane], bhn = bhh[128 + lane];
    int nbTot = (N + NB - 1) / NB;
    for (int nb = blockIdx.x * 8 + w; nb < nbTot; nb += gridDim.x * 8) {
        int n0 = nb * NB;
        float hv[NB];
#pragma unroll
        for (int n = 0; n < NB; ++n) {
            int i = n0 + n;
            hv[n] = (i < N) ? cur[(size_t)i * 64 + lane] : 0.f;
            xh[n * 64 + lane] = hv[n];
        }
#pragma unroll
        for (int n = 0; n < NB; ++n) {
            int i = n0 + n;
            float macc = 0.f;
            if (i < N) {
                float zb = z[(size_t)i * 64 + lane] + b;
                int s0 = row_start[i], s1 = row_start[i + 1];
                int s = s0;
                for (; s + 4 <= s1; s += 4) {
                    int e0 = csr_src[s], e1 = csr_src[s + 1];
                    int e2 = csr_src[s + 2], e3 = csr_src[s + 3];
                    float v0 = y[(size_t)e0 * 64 + lane];
                    float v1 = y[(size_t)e1 * 64 + lane];
                    float v2 = y[(size_t)e2 * 64 + lane];
                    float v3 = y[(size_t)e3 * 64 + lane];
                    macc += selu_f(v0 + zb);
                    macc += selu_f(v1 + zb);
                    macc += selu_f(v2 + zb);
                    macc += selu_f(v3 + zb);
                }
                for (; s < s1; ++s) macc += selu_f(y[(size_t)csr_src[s] * 64 + lane] + zb);
            }
            xm[n * 64 + lane] = macc;
        }
        float air[NB], aiz[NB], ain[NB], ahr[NB], ahz[NB], ahn[NB];
#pragma unroll
        for (int n = 0; n < NB; ++n) {
            air[n] = 0.f; aiz[n] = 0.f; ain[n] = 0.f;
            ahr[n] = 0.f; ahz[n] = 0.f; ahn[n] = 0.f;
        }
#pragma unroll 1
        for (int jg = 0; jg < 16; ++jg) {
            float4 wirv = *(const float4*)&wir[lane * WPAD + jg * 4];
            float4 wizv = *(const float4*)&wiz[lane * WPAD + jg * 4];
            float4 winv = *(const float4*)&win[lane * WPAD + jg * 4];
            float4 whrv = *(const float4*)&whr[lane * WPAD + jg * 4];
            float4 whzv = *(const float4*)&whz[lane * WPAD + jg * 4];
            float4 whnv = *(const float4*)&whn[lane * WPAD + jg * 4];
#pragma unroll
            for (int n = 0; n < NB; ++n) {
                float4 m4 = *(const float4*)&xm[n * 64 + jg * 4];  // uniform broadcast
                float4 h4 = *(const float4*)&xh[n * 64 + jg * 4];
                air[n] = dot4(wirv, m4, air[n]);
                aiz[n] = dot4(wizv, m4, aiz[n]);
                ain[n] = dot4(winv, m4, ain[n]);
                ahr[n] = dot4(whrv, h4, ahr[n]);
                ahz[n] = dot4(whzv, h4, ahz[n]);
                ahn[n] = dot4(whnv, h4, ahn[n]);
            }
        }
#pragma unroll
        for (int n = 0; n < NB; ++n) {
            int i = n0 + n;
            if (i < N) {
                float r = sigmoid_f(air[n] + bir + ahr[n] + bhr);
                float zg = sigmoid_f(aiz[n] + biz + ahz[n] + bhz);
                float nn = tanhf(ain[n] + bin_ + r * (ahn[n] + bhn));
                cur[(size_t)i * 64 + lane] = (1.f - zg) * nn + zg * hv[n];
            }
        }
    }
}

__global__ void __launch_bounds__(256) pathsum_kernel(const float* __restrict__ h,
                                                      float* __restrict__ kp, int N, int K) {
    int per = N / K;
    int blocksPerPath = gridDim.x / K;
    int p = blockIdx.x / blocksPerPath;
    int c = blockIdx.x % blocksPerPath;
    int d = threadIdx.x & 63;
    int row0 = c * (blockDim.x >> 6) + (threadIdx.x >> 6);
    int stride = blocksPerPath * (blockDim.x >> 6);
    float acc = 0.f;
    for (int r = row0; r < per; r += stride) acc += h[((size_t)p * per + r) * 64 + d];
    __shared__ float red[256];
    red[threadIdx.x] = acc;
    __syncthreads();
    if (threadIdx.x < 64) {
        float s = red[threadIdx.x] + red[64 + threadIdx.x] + red[128 + threadIdx.x] +
                  red[192 + threadIdx.x];
        atomicAdd(&kp[p * 64 + threadIdx.x], s);
    }
}

// 8 blocks, one per path: h1 = selu(kp@Wr1^T+br1); h2 = selu(h1@Wr2^T+br2)
__global__ void __launch_bounds__(256) readout1_kernel(const float* __restrict__ kp,
                                                       const float* __restrict__ Wr1,
                                                       const float* __restrict__ br1,
                                                       const float* __restrict__ Wr2,
                                                       const float* __restrict__ br2,
                                                       float* __restrict__ h2) {
    int p = blockIdx.x;
    int t = threadIdx.x;
    __shared__ __align__(16) float kps[64];
    __shared__ __align__(16) float h1[256];
    if (t < 64) kps[t] = kp[p * 64 + t];
    __syncthreads();
    float acc = br1[t];
#pragma unroll
    for (int d4 = 0; d4 < 16; ++d4) {
        float4 wv = *(const float4*)&Wr1[t * 64 + d4 * 4];
        float4 kv = *(const float4*)&kps[d4 * 4];
        acc = dot4(wv, kv, acc);
    }
    h1[t] = selu_f(acc);
    __syncthreads();
    float acc2 = br2[t];
#pragma unroll 8
    for (int j4 = 0; j4 < 64; ++j4) {
        float4 wv = *(const float4*)&Wr2[t * 256 + j4 * 4];
        float4 hv = *(const float4*)&h1[j4 * 4];
        acc2 = dot4(wv, hv, acc2);
    }
    h2[p * 256 + t] = selu_f(acc2);
}

__global__ void __launch_bounds__(256) readout2_kernel(const float* __restrict__ h2,
                                                       const float* __restrict__ Wr3,
                                                       const float* __restrict__ br3,
                                                       float* __restrict__ out) {
    __shared__ float red[256];
    __shared__ float lg[8];
    int t = threadIdx.x;
    float w3 = Wr3[t];
    for (int p = 0; p < 8; ++p) {
        red[t] = w3 * h2[p * 256 + t];
        __syncthreads();
        for (int off = 128; off > 0; off >>= 1) {
            if (t < off) red[t] += red[t + off];
            __syncthreads();
        }
        if (t == 0) lg[p] = red[0] + br3[0];
        __syncthreads();
    }
    if (t == 0) {
        float mx = lg[0];
        for (int p = 1; p < 8; ++p) mx = fmaxf(mx, lg[p]);
        float s = 0.f, e[8];
        for (int p = 0; p < 8; ++p) {
            e[p] = expf(lg[p] - mx);
            s += e[p];
        }
        for (int p = 0; p < 8; ++p) out[p] = e[p] / s;
    }
}

extern "C" void kernel_launch(void* const* d_in, const int* in_sizes, int n_in,
                              void* d_out, int out_size, void* d_ws, size_t ws_size,
                              hipStream_t stream) {
    const float* links_state = (const float*)d_in[0];
    const int* idm = (const int*)d_in[1];
    const int* idn = (const int*)d_in[2];
    const float* Wmsg = (const float*)d_in[3];
    const float* bmsg = (const float*)d_in[4];
    const float* Wih = (const float*)d_in[5];
    const float* Whh = (const float*)d_in[6];
    const float* bih = (const float*)d_in[7];
    const float* bhh = (const float*)d_in[8];
    const float* Wr1 = (const float*)d_in[9];
    const float* br1 = (const float*)d_in[10];
    const float* Wr2 = (const float*)d_in[11];
    const float* br2 = (const float*)d_in[12];
    const float* Wr3 = (const float*)d_in[13];
    const float* br3 = (const float*)d_in[14];

    const int N = in_sizes[0] / D;  // 50000
    const int E = in_sizes[1];      // 800000
    const int K = 8, T = 3;

    float* ws = (float*)d_ws;
    size_t nd = (size_t)N * D;
    float* cur = ws;
    float* y = ws + nd;
    float* z = ws + 2 * nd;
    float* kp = ws + 3 * nd;       // 512
    float* h2 = kp + 512;          // 2048
    int* ibase = (int*)(h2 + 2048);
    int* cnt = ibase;                  // N
    int* row_start = ibase + N;        // N+1
    int* cursor = ibase + 2 * N + 1;   // N
    int* csr_src = ibase + 3 * N + 1;  // E

    // CSR build (once per launch)
    hipMemsetAsync(cnt, 0, (size_t)N * sizeof(int), stream);
    hipMemsetAsync(cursor, 0, (size_t)N * sizeof(int), stream);
    count_kernel<<<dim3((E + 255) / 256), dim3(256), 0, stream>>>(idn, cnt, E);
    scan_kernel<<<dim3(1), dim3(1024), 0, stream>>>(cnt, row_start, N);
    fill_kernel<<<dim3((E + 255) / 256), dim3(256), 0, stream>>>(idm, idn, row_start, cursor,
                                                                 csr_src, E);

    hipMemcpyAsync(cur, links_state, nd * sizeof(float), hipMemcpyDeviceToDevice, stream);

    int nbTot = (N + NB - 1) / NB;         // 6250
    int gridA = (nbTot + 15) / 16;         // 391
    int gridB = (nbTot + 7) / 8;           // 782
    for (int t = 0; t < T; ++t) {
        yz_kernel<<<dim3(gridA), dim3(1024), 0, stream>>>(cur, Wmsg, y, z, N);
        step_kernel<<<dim3(gridB), dim3(512), 0, stream>>>(y, z, cur, bmsg, row_start,
                                                           csr_src, Wih, Whh, bih, bhh, N);
    }

    hipMemsetAsync(kp, 0, (size_t)K * 64 * sizeof(float), stream);
    pathsum_kernel<<<dim3(256), dim3(256), 0, stream>>>(cur, kp, N, K);
    readout1_kernel<<<dim3(8), dim3(256), 0, stream>>>(kp, Wr1, br1, Wr2, br2, h2);
    readout2_kernel<<<dim3(1), dim3(256), 0, stream>>>(h2, Wr3, br3, (float*)d_out);
}